// Round 1
// baseline (617.795 us; speedup 1.0000x reference)
//
#include <hip/hip_runtime.h>

#define EMB 64
#define DICT 512
#define HW 4096              // 64*64
#define NPTS (32 * HW)       // 131072
#define MOM 0.99f
#define OMOM 0.01f
#define EPSV 1e-5f

// ws layout (float offsets)
#define WS_COMMIT 0
#define WS_COUNTS 64                      // 512 floats
#define WS_ESUM   1024                    // 64*512 = 32768 floats
#define WS_EE     (1024 + EMB * DICT)     // 512 floats (written by vq_ee, not zeroed)
#define WS_N      (WS_EE + DICT)          // 1 float
#define WS_ZERO_FLOATS WS_EE              // zero first 33792 floats each call

// ---------------------------------------------------------------- ||e_j||^2
__global__ __launch_bounds__(512) void vq_ee(const float* __restrict__ embed,
                                             float* __restrict__ ee) {
    int j = threadIdx.x;
    if (j >= DICT) return;
    float s = 0.f;
    #pragma unroll
    for (int ch = 0; ch < EMB; ++ch) {
        float v = embed[j * EMB + ch];
        s = fmaf(v, v, s);
    }
    ee[j] = s;
}

// ---------------------------------------------------------------- main kernel
// grid: 512 blocks of 256 threads; block = (b, h0..h0+3) x all w; thread = 1 point
__global__ __launch_bounds__(256) void vq_main(
    const float* __restrict__ input, const float* __restrict__ embed,
    const float* __restrict__ ee, float* __restrict__ out_q,
    float* __restrict__ out_ids, float* __restrict__ ws) {
    __shared__ float cnt[DICT];
    __shared__ float commit_s;

    int t = threadIdx.x;
    for (int i = t; i < DICT; i += 256) cnt[i] = 0.f;
    if (t == 0) commit_s = 0.f;
    __syncthreads();

    int blk = blockIdx.x;
    int b   = blk >> 4;
    int h0  = (blk & 15) << 2;
    int w_i = t & 63;
    int h_i = h0 + (t >> 6);

    // x[ch] = input[b][ch][h_i][w_i]; lanes consecutive in w -> coalesced
    const float* xp = input + (size_t)b * (EMB * HW) + h_i * 64 + w_i;
    float x[EMB];
    #pragma unroll
    for (int ch = 0; ch < EMB; ++ch) x[ch] = xp[(size_t)ch * HW];

    // argmax_j ( 2*x.e_j - ||e_j||^2 ), first-index tie-break
    float best = -3.0e38f;
    int bidx = 0;
    #pragma unroll 2
    for (int j = 0; j < DICT; ++j) {
        const float* er = embed + j * EMB;   // uniform across lanes -> s_load
        float d0 = 0.f, d1 = 0.f, d2 = 0.f, d3 = 0.f;
        #pragma unroll
        for (int ch = 0; ch < EMB; ch += 4) {
            d0 = fmaf(er[ch + 0], x[ch + 0], d0);
            d1 = fmaf(er[ch + 1], x[ch + 1], d1);
            d2 = fmaf(er[ch + 2], x[ch + 2], d2);
            d3 = fmaf(er[ch + 3], x[ch + 3], d3);
        }
        float s = fmaf(2.f, (d0 + d1) + (d2 + d3), -ee[j]);
        if (s > best) { best = s; bidx = j; }
    }

    // quantized write + exact commit contribution
    size_t qbase = (size_t)b * (EMB * HW) + h_i * 64 + w_i;
    const float* eb = embed + bidx * EMB;    // per-lane gather (L2-resident)
    float cl = 0.f;
    #pragma unroll
    for (int ch = 0; ch < EMB; ++ch) {
        float q = eb[ch];
        out_q[qbase + (size_t)ch * HW] = q;
        float dv = x[ch] - q;
        cl = fmaf(dv, dv, cl);
    }

    // ids: flat order n = b*4096 + w*64 + h  (the (b,w,h) flatten quirk)
    out_ids[b * HW + w_i * 64 + h_i] = (float)bidx;

    // commit loss: wave shuffle-reduce, then one LDS atomic per wave
    #pragma unroll
    for (int off = 32; off > 0; off >>= 1) cl += __shfl_down(cl, off);
    if ((t & 63) == 0) atomicAdd(&commit_s, cl);

    // counts into LDS
    atomicAdd(&cnt[bidx], 1.0f);

    // embed_sum[ch][bidx] global atomics
    float* esum = ws + WS_ESUM;
    #pragma unroll
    for (int ch = 0; ch < EMB; ++ch) {
        unsafeAtomicAdd(&esum[ch * DICT + bidx], x[ch]);
    }

    __syncthreads();
    for (int i = t; i < DICT; i += 256) {
        float c = cnt[i];
        if (c != 0.f) unsafeAtomicAdd(&ws[WS_COUNTS + i], c);
    }
    if (t == 0) unsafeAtomicAdd(&ws[WS_COMMIT], commit_s);
}

// ---------------------------------------------------------------- finalize 1
__global__ __launch_bounds__(512) void vq_fin1(
    const float* __restrict__ cluster_size, float* __restrict__ ws,
    float* __restrict__ out_cs, float* __restrict__ out_loss) {
    __shared__ float red[DICT];
    int d = threadIdx.x;
    float ncs = cluster_size[d] * MOM + ws[WS_COUNTS + d] * OMOM;
    out_cs[d] = ncs;
    red[d] = ncs;
    __syncthreads();
    #pragma unroll
    for (int off = 256; off > 0; off >>= 1) {
        if (d < off) red[d] += red[d + off];
        __syncthreads();
    }
    if (d == 0) {
        ws[WS_N] = red[0];
        out_loss[0] = ws[WS_COMMIT] * (1.0f / (float)((size_t)NPTS * EMB));
    }
}

// ---------------------------------------------------------------- finalize 2
__global__ __launch_bounds__(256) void vq_fin2(
    const float* __restrict__ embed_avg, const float* __restrict__ cluster_size,
    const float* __restrict__ ws, float* __restrict__ out_embed,
    float* __restrict__ out_avg) {
    int idx = blockIdx.x * 256 + threadIdx.x;  // idx = ch*512 + d
    int ch = idx >> 9, d = idx & 511;
    float avg = embed_avg[idx] * MOM + ws[WS_ESUM + idx] * OMOM;
    out_avg[idx] = avg;
    float n = ws[WS_N];
    float ncs = cluster_size[d] * MOM + ws[WS_COUNTS + d] * OMOM;
    float cs = n * (ncs + EPSV) / (n + (float)DICT * EPSV);
    out_embed[d * EMB + ch] = avg / cs;
}

extern "C" void kernel_launch(void* const* d_in, const int* in_sizes, int n_in,
                              void* d_out, int out_size, void* d_ws, size_t ws_size,
                              hipStream_t stream) {
    const float* input        = (const float*)d_in[0];
    const float* embed        = (const float*)d_in[1];
    const float* cluster_size = (const float*)d_in[2];
    const float* embed_avg    = (const float*)d_in[3];

    float* out   = (float*)d_out;
    float* q     = out;                         // 8388608
    float* loss  = out + 8388608;               // 1
    float* ids   = out + 8388609;               // 131072
    float* oemb  = out + 8519681;               // 32768
    float* ocs   = out + 8552449;               // 512
    float* oavg  = out + 8552961;               // 32768
    float* ws    = (float*)d_ws;

    hipMemsetAsync(d_ws, 0, (size_t)WS_ZERO_FLOATS * sizeof(float), stream);
    vq_ee  <<<1, 512, 0, stream>>>(embed, ws + WS_EE);
    vq_main<<<512, 256, 0, stream>>>(input, embed, ws + WS_EE, q, ids, ws);
    vq_fin1<<<1, 512, 0, stream>>>(cluster_size, ws, ocs, loss);
    vq_fin2<<<128, 256, 0, stream>>>(embed_avg, cluster_size, ws, oemb, oavg);
}

// Round 2
// 559.625 us; speedup vs baseline: 1.1039x; 1.1039x over previous
//
#include <hip/hip_runtime.h>

#define EMB 64
#define DICT 512
#define HW 4096              // 64*64
#define NPTS (32 * HW)       // 131072
#define MOM 0.99f
#define OMOM 0.01f
#define EPSV 1e-5f

typedef float v2f __attribute__((ext_vector_type(2)));
typedef float v4f __attribute__((ext_vector_type(4)));

// ws layout (float offsets)
#define WS_COMMIT 0
#define WS_COUNTS 64                      // 512 floats
#define WS_ESUM   1024                    // 64*512 = 32768 floats
#define WS_EE     (1024 + EMB * DICT)     // 512 floats (written by vq_ee, not zeroed)
#define WS_N      (WS_EE + DICT)          // 1 float
#define WS_ZERO_FLOATS WS_EE              // zero first 33792 floats each call

// ---------------------------------------------------------------- ||e_j||^2
__global__ __launch_bounds__(512) void vq_ee(const float* __restrict__ embed,
                                             float* __restrict__ ee) {
    int j = threadIdx.x;
    if (j >= DICT) return;
    float s = 0.f;
    #pragma unroll
    for (int ch = 0; ch < EMB; ++ch) {
        float v = embed[j * EMB + ch];
        s = fmaf(v, v, s);
    }
    ee[j] = s;
}

// ---------------------------------------------------------------- main kernel
// grid: 512 blocks of 256 threads; block = (b, h0..h0+3) x all w; thread = 1 point
__global__ __launch_bounds__(256) void vq_main(
    const float* __restrict__ input, const float* __restrict__ embed,
    const float* __restrict__ ee, float* __restrict__ out_q,
    float* __restrict__ out_ids, float* __restrict__ ws) {
    __shared__ float cnt[DICT];
    __shared__ float commit_s;

    int t = threadIdx.x;
    for (int i = t; i < DICT; i += 256) cnt[i] = 0.f;
    if (t == 0) commit_s = 0.f;
    __syncthreads();

    int blk = blockIdx.x;
    int b   = blk >> 4;
    int h0  = (blk & 15) << 2;
    int w_i = t & 63;
    int h_i = h0 + (t >> 6);

    // x2[c] = channels (2c, 2c+1) of input[b][:][h_i][w_i]; lanes consecutive in w
    const float* xp = input + (size_t)b * (EMB * HW) + h_i * 64 + w_i;
    v2f x2[32];
    #pragma unroll
    for (int c = 0; c < 32; ++c) {
        v2f tv;
        tv.x = xp[(size_t)(2 * c) * HW];
        tv.y = xp[(size_t)(2 * c + 1) * HW];
        x2[c] = tv;
    }
    // Pin x in VGPRs: block rematerialization of the (invariant) global loads.
    #pragma unroll
    for (int c = 0; c < 32; ++c) asm volatile("" : "+v"(x2[c]));

    // argmax_j ( 2*x.e_j - ||e_j||^2 ), first-index tie-break
    float best = -3.0e38f;
    int bidx = 0;
    #pragma unroll 2
    for (int j = 0; j < DICT; ++j) {
        const v4f* e4 = (const v4f*)(embed + j * EMB);  // uniform addr -> L1 broadcast
        v2f aA0 = {0.f, 0.f}, aA1 = {0.f, 0.f}, aA2 = {0.f, 0.f}, aA3 = {0.f, 0.f};
        v2f aB0 = {0.f, 0.f}, aB1 = {0.f, 0.f}, aB2 = {0.f, 0.f}, aB3 = {0.f, 0.f};
        #pragma unroll
        for (int k = 0; k < 16; k += 4) {
            v4f e0 = e4[k + 0], e1 = e4[k + 1], e2 = e4[k + 2], e3 = e4[k + 3];
            v2f lo0 = {e0.x, e0.y}, hi0 = {e0.z, e0.w};
            v2f lo1 = {e1.x, e1.y}, hi1 = {e1.z, e1.w};
            v2f lo2 = {e2.x, e2.y}, hi2 = {e2.z, e2.w};
            v2f lo3 = {e3.x, e3.y}, hi3 = {e3.z, e3.w};
            aA0 = __builtin_elementwise_fma(lo0, x2[2 * k + 0], aA0);
            aB0 = __builtin_elementwise_fma(hi0, x2[2 * k + 1], aB0);
            aA1 = __builtin_elementwise_fma(lo1, x2[2 * k + 2], aA1);
            aB1 = __builtin_elementwise_fma(hi1, x2[2 * k + 3], aB1);
            aA2 = __builtin_elementwise_fma(lo2, x2[2 * k + 4], aA2);
            aB2 = __builtin_elementwise_fma(hi2, x2[2 * k + 5], aB2);
            aA3 = __builtin_elementwise_fma(lo3, x2[2 * k + 6], aA3);
            aB3 = __builtin_elementwise_fma(hi3, x2[2 * k + 7], aB3);
        }
        v2f r = ((aA0 + aA1) + (aA2 + aA3)) + ((aB0 + aB1) + (aB2 + aB3));
        float s = fmaf(2.f, r.x + r.y, -ee[j]);
        if (s > best) { best = s; bidx = j; }
    }

    // quantized write + exact commit contribution (re-gather best row as float4)
    size_t qbase = (size_t)b * (EMB * HW) + h_i * 64 + w_i;
    const v4f* ebr = (const v4f*)(embed + bidx * EMB);   // per-lane gather (L2-resident)
    float cl = 0.f;
    float xq[EMB];
    #pragma unroll
    for (int c = 0; c < 32; ++c) { xq[2 * c] = x2[c].x; xq[2 * c + 1] = x2[c].y; }
    #pragma unroll
    for (int k = 0; k < 16; ++k) {
        v4f q = ebr[k];
        out_q[qbase + (size_t)(4 * k + 0) * HW] = q.x;
        out_q[qbase + (size_t)(4 * k + 1) * HW] = q.y;
        out_q[qbase + (size_t)(4 * k + 2) * HW] = q.z;
        out_q[qbase + (size_t)(4 * k + 3) * HW] = q.w;
        float d0 = xq[4 * k + 0] - q.x, d1 = xq[4 * k + 1] - q.y;
        float d2 = xq[4 * k + 2] - q.z, d3 = xq[4 * k + 3] - q.w;
        cl = fmaf(d0, d0, cl); cl = fmaf(d1, d1, cl);
        cl = fmaf(d2, d2, cl); cl = fmaf(d3, d3, cl);
    }

    // ids: flat order n = b*4096 + w*64 + h  (the (b,w,h) flatten quirk)
    out_ids[b * HW + w_i * 64 + h_i] = (float)bidx;

    // commit loss: wave shuffle-reduce, then one LDS atomic per wave
    #pragma unroll
    for (int off = 32; off > 0; off >>= 1) cl += __shfl_down(cl, off);
    if ((t & 63) == 0) atomicAdd(&commit_s, cl);

    // counts into LDS
    atomicAdd(&cnt[bidx], 1.0f);

    // embed_sum[ch][bidx] global atomics
    float* esum = ws + WS_ESUM;
    #pragma unroll
    for (int c = 0; c < EMB; ++c) {
        unsafeAtomicAdd(&esum[c * DICT + bidx], xq[c]);
    }

    __syncthreads();
    for (int i = t; i < DICT; i += 256) {
        float c = cnt[i];
        if (c != 0.f) unsafeAtomicAdd(&ws[WS_COUNTS + i], c);
    }
    if (t == 0) unsafeAtomicAdd(&ws[WS_COMMIT], commit_s);
}

// ---------------------------------------------------------------- finalize 1
__global__ __launch_bounds__(512) void vq_fin1(
    const float* __restrict__ cluster_size, float* __restrict__ ws,
    float* __restrict__ out_cs, float* __restrict__ out_loss) {
    __shared__ float red[DICT];
    int d = threadIdx.x;
    float ncs = cluster_size[d] * MOM + ws[WS_COUNTS + d] * OMOM;
    out_cs[d] = ncs;
    red[d] = ncs;
    __syncthreads();
    #pragma unroll
    for (int off = 256; off > 0; off >>= 1) {
        if (d < off) red[d] += red[d + off];
        __syncthreads();
    }
    if (d == 0) {
        ws[WS_N] = red[0];
        out_loss[0] = ws[WS_COMMIT] * (1.0f / (float)((size_t)NPTS * EMB));
    }
}

// ---------------------------------------------------------------- finalize 2
__global__ __launch_bounds__(256) void vq_fin2(
    const float* __restrict__ embed_avg, const float* __restrict__ cluster_size,
    const float* __restrict__ ws, float* __restrict__ out_embed,
    float* __restrict__ out_avg) {
    int idx = blockIdx.x * 256 + threadIdx.x;  // idx = ch*512 + d
    int ch = idx >> 9, d = idx & 511;
    float avg = embed_avg[idx] * MOM + ws[WS_ESUM + idx] * OMOM;
    out_avg[idx] = avg;
    float n = ws[WS_N];
    float ncs = cluster_size[d] * MOM + ws[WS_COUNTS + d] * OMOM;
    float cs = n * (ncs + EPSV) / (n + (float)DICT * EPSV);
    out_embed[d * EMB + ch] = avg / cs;
}

extern "C" void kernel_launch(void* const* d_in, const int* in_sizes, int n_in,
                              void* d_out, int out_size, void* d_ws, size_t ws_size,
                              hipStream_t stream) {
    const float* input        = (const float*)d_in[0];
    const float* embed        = (const float*)d_in[1];
    const float* cluster_size = (const float*)d_in[2];
    const float* embed_avg    = (const float*)d_in[3];

    float* out   = (float*)d_out;
    float* q     = out;                         // 8388608
    float* loss  = out + 8388608;               // 1
    float* ids   = out + 8388609;               // 131072
    float* oemb  = out + 8519681;               // 32768
    float* ocs   = out + 8552449;               // 512
    float* oavg  = out + 8552961;               // 32768
    float* ws    = (float*)d_ws;

    hipMemsetAsync(d_ws, 0, (size_t)WS_ZERO_FLOATS * sizeof(float), stream);
    vq_ee  <<<1, 512, 0, stream>>>(embed, ws + WS_EE);
    vq_main<<<512, 256, 0, stream>>>(input, embed, ws + WS_EE, q, ids, ws);
    vq_fin1<<<1, 512, 0, stream>>>(cluster_size, ws, ocs, loss);
    vq_fin2<<<128, 256, 0, stream>>>(embed_avg, cluster_size, ws, oemb, oavg);
}

// Round 3
// 215.937 us; speedup vs baseline: 2.8610x; 2.5916x over previous
//
#include <hip/hip_runtime.h>

#define EMB 64
#define DICT 512
#define HW 4096              // 64*64
#define NPTS (32 * HW)       // 131072
#define MOM 0.99f
#define OMOM 0.01f
#define EPSV 1e-5f

typedef float v2f __attribute__((ext_vector_type(2)));
typedef float v4f __attribute__((ext_vector_type(4)));

// ws layout (float offsets)
#define WS_COMMIT 0
#define WS_COUNTS 64                      // 512
#define WS_ESUM   1024                    // 64*512 = 32768 (esum[ch*512+j])
#define WS_ZERO_FLOATS 33792              // zero [0, 33792) each call
#define WS_EE     33792                   // 512
#define WS_N      34304                   // 1
#define WS_ET     34320                   // 64*512 = 32768 (ET[ch*512+j] = embed[j][ch])
#define WS_IDS    67088                   // 131072 ints (natural pixel order)

// ------------------------------------------------- prep: embed^T + ||e||^2
__global__ __launch_bounds__(256) void vq_prep(const float* __restrict__ embed,
                                               float* __restrict__ et,
                                               float* __restrict__ ee) {
    __shared__ float tl[64][65];
    int t = threadIdx.x;
    int j0 = blockIdx.x * 64;
    #pragma unroll
    for (int i = 0; i < 16; ++i) {
        int idx = t + i * 256;
        int jj = idx >> 6, ch = idx & 63;
        tl[jj][ch] = embed[(j0 + jj) * 64 + ch];
    }
    __syncthreads();
    #pragma unroll
    for (int i = 0; i < 16; ++i) {
        int idx = t + i * 256;
        int ch_o = idx >> 6, jj_o = idx & 63;
        et[ch_o * 512 + j0 + jj_o] = tl[jj_o][ch_o];
    }
    if (t < 64) {
        float s = 0.f;
        #pragma unroll
        for (int ch = 0; ch < 64; ++ch) s = fmaf(tl[t][ch], tl[t][ch], s);
        ee[j0 + t] = s;
    }
}

// ------------------------------------------------- argmax GEMM kernel
// block: 128 points x 128-code tiles, K=64 staged in LDS; thread: 8x8 tile.
__global__ __launch_bounds__(256, 2) void vq_argmax(
    const float* __restrict__ input, const float* __restrict__ et,
    const float* __restrict__ ee, float* __restrict__ out_ids,
    int* __restrict__ ws_ids) {
    __shared__ float Xs[64 * 128];   // Xs[k][p]
    __shared__ float Es[64 * 128];   // Es[k][j2]

    int t  = threadIdx.x;
    int tx = t & 15;                 // code octet
    int ty = t >> 4;                 // point octet
    int blk = blockIdx.x;
    int b   = blk >> 5;
    int h2  = blk & 31;              // 2 h-rows per block

    // stage X: Xs[ch][p] = input[b][ch][h2*128 + p], p in [0,128)
    const float* xg = input + (size_t)b * (EMB * HW) + h2 * 128;
    #pragma unroll
    for (int i = 0; i < 8; ++i) {
        int idx = t + i * 256;                 // float4 index, 2048 total
        int ch = idx >> 5, p4 = (idx & 31) << 2;
        v4f v = *(const v4f*)(xg + (size_t)ch * HW + p4);
        *(v4f*)&Xs[idx * 4] = v;
    }

    float best[8];
    int   bid[8];
    #pragma unroll
    for (int p = 0; p < 8; ++p) { best[p] = -3.0e38f; bid[p] = 0; }

    for (int jt = 0; jt < 4; ++jt) {
        int j0 = jt * 128;
        // stage E tile: Es[ch][j2] = et[ch*512 + j0 + j2]
        const float* eg = et + j0;
        #pragma unroll
        for (int i = 0; i < 8; ++i) {
            int idx = t + i * 256;
            int ch = idx >> 5, j24 = (idx & 31) << 2;
            v4f v = *(const v4f*)(eg + ch * 512 + j24);
            *(v4f*)&Es[idx * 4] = v;
        }
        __syncthreads();

        float ee8[8];
        #pragma unroll
        for (int jj = 0; jj < 8; ++jj) ee8[jj] = ee[j0 + (tx << 3) + jj];

        v2f acc[8][4];
        #pragma unroll
        for (int p = 0; p < 8; ++p)
            #pragma unroll
            for (int q = 0; q < 4; ++q) acc[p][q] = (v2f){0.f, 0.f};

        #pragma unroll 4
        for (int k = 0; k < 64; ++k) {
            v4f a0 = *(const v4f*)&Xs[k * 128 + (ty << 3)];
            v4f a1 = *(const v4f*)&Xs[k * 128 + (ty << 3) + 4];
            v4f b0 = *(const v4f*)&Es[k * 128 + (tx << 3)];
            v4f b1 = *(const v4f*)&Es[k * 128 + (tx << 3) + 4];
            v2f b2[4] = {{b0.x, b0.y}, {b0.z, b0.w}, {b1.x, b1.y}, {b1.z, b1.w}};
            float av[8] = {a0.x, a0.y, a0.z, a0.w, a1.x, a1.y, a1.z, a1.w};
            #pragma unroll
            for (int p = 0; p < 8; ++p) {
                v2f ap = {av[p], av[p]};
                #pragma unroll
                for (int q = 0; q < 4; ++q)
                    acc[p][q] = __builtin_elementwise_fma(ap, b2[q], acc[p][q]);
            }
        }

        // fold -||e||^2, running argmax (j ascending -> first-index tie-break)
        int jb = j0 + (tx << 3);
        #pragma unroll
        for (int p = 0; p < 8; ++p) {
            #pragma unroll
            for (int q = 0; q < 4; ++q) {
                float s0 = fmaf(2.f, acc[p][q].x, -ee8[2 * q]);
                if (s0 > best[p]) { best[p] = s0; bid[p] = jb + 2 * q; }
                float s1 = fmaf(2.f, acc[p][q].y, -ee8[2 * q + 1]);
                if (s1 > best[p]) { best[p] = s1; bid[p] = jb + 2 * q + 1; }
            }
        }
        __syncthreads();   // before overwriting Es next tile
    }

    // reduce over the 16 tx lanes sharing each point group
    #pragma unroll
    for (int p = 0; p < 8; ++p) {
        float bb = best[p];
        int   bi = bid[p];
        #pragma unroll
        for (int off = 8; off > 0; off >>= 1) {
            float ob = __shfl_xor(bb, off, 16);
            int   oi = __shfl_xor(bi, off, 16);
            if (ob > bb || (ob == bb && oi < bi)) { bb = ob; bi = oi; }
        }
        if (tx == 0) {
            int pl = (ty << 3) + p;            // local point 0..127
            int h = (h2 << 1) + (pl >> 6);
            int w = pl & 63;
            ws_ids[b * HW + h2 * 128 + pl] = bi;            // natural order
            out_ids[b * HW + w * 64 + h] = (float)bi;       // (b,w,h) quirk
        }
    }
}

// ------------------------------------------------- scatter / stats kernel
// block = (b, ch): coalesced input/quantized; LDS-aggregated esum/counts.
__global__ __launch_bounds__(256) void vq_scatter(
    const float* __restrict__ input, const float* __restrict__ embed,
    const int* __restrict__ ws_ids, float* __restrict__ out_q,
    float* __restrict__ ws) {
    __shared__ float esum_s[DICT];
    __shared__ float cnt_s[DICT];
    __shared__ float commit_s;

    int t = threadIdx.x;
    int bc = blockIdx.x;
    int b = bc >> 6, ch = bc & 63;

    for (int i = t; i < DICT; i += 256) { esum_s[i] = 0.f; cnt_s[i] = 0.f; }
    if (t == 0) commit_s = 0.f;
    __syncthreads();

    const float* xg = input + (size_t)b * (EMB * HW) + (size_t)ch * HW;
    float*       qg = out_q + (size_t)b * (EMB * HW) + (size_t)ch * HW;
    const int*  idg = ws_ids + b * HW;

    float cl = 0.f;
    #pragma unroll
    for (int i = 0; i < 4; ++i) {
        int idx4 = (t + i * 256) * 4;
        v4f x = *(const v4f*)(xg + idx4);
        int4 id = *(const int4*)(idg + idx4);
        float q0 = embed[id.x * 64 + ch];
        float q1 = embed[id.y * 64 + ch];
        float q2 = embed[id.z * 64 + ch];
        float q3 = embed[id.w * 64 + ch];
        v4f qv = {q0, q1, q2, q3};
        *(v4f*)(qg + idx4) = qv;
        float d0 = x.x - q0, d1 = x.y - q1, d2 = x.z - q2, d3 = x.w - q3;
        cl = fmaf(d0, d0, cl); cl = fmaf(d1, d1, cl);
        cl = fmaf(d2, d2, cl); cl = fmaf(d3, d3, cl);
        atomicAdd(&esum_s[id.x], x.x);
        atomicAdd(&esum_s[id.y], x.y);
        atomicAdd(&esum_s[id.z], x.z);
        atomicAdd(&esum_s[id.w], x.w);
        if (ch == 0) {
            atomicAdd(&cnt_s[id.x], 1.f);
            atomicAdd(&cnt_s[id.y], 1.f);
            atomicAdd(&cnt_s[id.z], 1.f);
            atomicAdd(&cnt_s[id.w], 1.f);
        }
    }

    #pragma unroll
    for (int off = 32; off > 0; off >>= 1) cl += __shfl_down(cl, off);
    if ((t & 63) == 0) atomicAdd(&commit_s, cl);
    __syncthreads();

    for (int i = t; i < DICT; i += 256) {
        float v = esum_s[i];
        if (v != 0.f) unsafeAtomicAdd(&ws[WS_ESUM + ch * DICT + i], v);
        if (ch == 0) {
            float c = cnt_s[i];
            if (c != 0.f) unsafeAtomicAdd(&ws[WS_COUNTS + i], c);
        }
    }
    if (t == 0) unsafeAtomicAdd(&ws[WS_COMMIT], commit_s);
}

// ---------------------------------------------------------------- finalize 1
__global__ __launch_bounds__(512) void vq_fin1(
    const float* __restrict__ cluster_size, float* __restrict__ ws,
    float* __restrict__ out_cs, float* __restrict__ out_loss) {
    __shared__ float red[DICT];
    int d = threadIdx.x;
    float ncs = cluster_size[d] * MOM + ws[WS_COUNTS + d] * OMOM;
    out_cs[d] = ncs;
    red[d] = ncs;
    __syncthreads();
    #pragma unroll
    for (int off = 256; off > 0; off >>= 1) {
        if (d < off) red[d] += red[d + off];
        __syncthreads();
    }
    if (d == 0) {
        ws[WS_N] = red[0];
        out_loss[0] = ws[WS_COMMIT] * (1.0f / (float)((size_t)NPTS * EMB));
    }
}

// ---------------------------------------------------------------- finalize 2
__global__ __launch_bounds__(256) void vq_fin2(
    const float* __restrict__ embed_avg, const float* __restrict__ cluster_size,
    const float* __restrict__ ws, float* __restrict__ out_embed,
    float* __restrict__ out_avg) {
    int idx = blockIdx.x * 256 + threadIdx.x;  // idx = ch*512 + d
    int ch = idx >> 9, d = idx & 511;
    float avg = embed_avg[idx] * MOM + ws[WS_ESUM + idx] * OMOM;
    out_avg[idx] = avg;
    float n = ws[WS_N];
    float ncs = cluster_size[d] * MOM + ws[WS_COUNTS + d] * OMOM;
    float cs = n * (ncs + EPSV) / (n + (float)DICT * EPSV);
    out_embed[d * EMB + ch] = avg / cs;
}

extern "C" void kernel_launch(void* const* d_in, const int* in_sizes, int n_in,
                              void* d_out, int out_size, void* d_ws, size_t ws_size,
                              hipStream_t stream) {
    const float* input        = (const float*)d_in[0];
    const float* embed        = (const float*)d_in[1];
    const float* cluster_size = (const float*)d_in[2];
    const float* embed_avg    = (const float*)d_in[3];

    float* out   = (float*)d_out;
    float* q     = out;                         // 8388608
    float* loss  = out + 8388608;               // 1
    float* ids   = out + 8388609;               // 131072
    float* oemb  = out + 8519681;               // 32768
    float* ocs   = out + 8552449;               // 512
    float* oavg  = out + 8552961;               // 32768
    float* ws    = (float*)d_ws;

    hipMemsetAsync(d_ws, 0, (size_t)WS_ZERO_FLOATS * sizeof(float), stream);
    vq_prep   <<<8, 256, 0, stream>>>(embed, ws + WS_ET, ws + WS_EE);
    vq_argmax <<<1024, 256, 0, stream>>>(input, ws + WS_ET, ws + WS_EE,
                                         ids, (int*)(ws + WS_IDS));
    vq_scatter<<<2048, 256, 0, stream>>>(input, embed, (const int*)(ws + WS_IDS),
                                         q, ws);
    vq_fin1   <<<1, 512, 0, stream>>>(cluster_size, ws, ocs, loss);
    vq_fin2   <<<128, 256, 0, stream>>>(embed_avg, cluster_size, ws, oemb, oavg);
}